// Round 7
// baseline (571.047 us; speedup 1.0000x reference)
//
#include <hip/hip_runtime.h>
#include <hip/hip_bf16.h>
#include <stdint.h>

// ---------------------------------------------------------------------------
// MHA: out = (softmax((xWq^T)(xWk^T)^T / 8) (xWv^T)) Wo^T  + attn matrix out
// B=4 S=1024 H=16 D=64 DM=1024.
// d_out = [ out (B,S,DM) fp32 | attn (B,H,S,S) fp32 ]
// ws (big, >=59MB): [ xq xk xv | Wb(4) | Qb Kb Vt ] bf16, ctx overlays xq.
// ws (small):      [ Qb Kb Vt ctx | Wb(4) ] bf16 (42MB).
// ---------------------------------------------------------------------------

#define DEV static __device__ __forceinline__

typedef __bf16 bf16x8 __attribute__((ext_vector_type(8)));
typedef float f32x4 __attribute__((ext_vector_type(4)));
typedef unsigned short u16x8 __attribute__((ext_vector_type(8)));

static constexpr int B = 4, S = 1024, H = 16, D = 64, DM = 1024, M = 4096;
static constexpr size_t NQ = (size_t)M * DM; // 4194304 elements

DEV uint16_t f2bf_bits(float f) {
    __hip_bfloat16 h = __float2bfloat16(f); // RNE
    return __builtin_bit_cast(uint16_t, h);
}
DEV uint64_t pack4(float4 v) {
    return (uint64_t)f2bf_bits(v.x) | ((uint64_t)f2bf_bits(v.y) << 16) |
           ((uint64_t)f2bf_bits(v.z) << 32) | ((uint64_t)f2bf_bits(v.w) << 48);
}
DEV uint64_t pack4f(const f32x4& v) {
    return (uint64_t)f2bf_bits(v[0]) | ((uint64_t)f2bf_bits(v[1]) << 16) |
           ((uint64_t)f2bf_bits(v[2]) << 32) | ((uint64_t)f2bf_bits(v[3]) << 48);
}
DEV bf16x8 ldfrag(const uint16_t* p) { // p must be 16B aligned
    u16x8 t = *(const u16x8*)p;
    return __builtin_bit_cast(bf16x8, t);
}

#define GLOAD16(g, l)                                                  \
    __builtin_amdgcn_global_load_lds(                                  \
        (const __attribute__((address_space(1))) void*)(g),            \
        (__attribute__((address_space(3))) void*)(l), 16, 0, 0)

#define MFMA16(a, b, c) __builtin_amdgcn_mfma_f32_16x16x32_bf16(a, b, c, 0, 0, 0)

// ---------------------------------------------------------------------------
// cvt_all (big ws): convert q,k,v,Wq,Wk,Wv,Wo fp32 -> bf16.  grid (2048, 7).
// ---------------------------------------------------------------------------
__global__ __launch_bounds__(256) void cvt_all(const float* __restrict__ q,
                                               const float* __restrict__ k,
                                               const float* __restrict__ v,
                                               const float* __restrict__ wq,
                                               const float* __restrict__ wk,
                                               const float* __restrict__ wv,
                                               const float* __restrict__ wo,
                                               uint16_t* __restrict__ dst) {
    const int y = blockIdx.y;
    const float* srcs[7] = {q, k, v, wq, wk, wv, wo};
    const float* src = srcs[y];
    const size_t base = y < 3 ? (size_t)y * NQ : 3 * NQ + (size_t)(y - 3) * (DM * DM);
    const size_t n = y < 3 ? NQ : (size_t)DM * DM;
    size_t i = ((size_t)blockIdx.x * 256 + threadIdx.x) * 8;
    if (i >= n) return;
    float4 a = *(const float4*)(src + i);
    float4 b2 = *(const float4*)(src + i + 4);
    *(uint64_t*)(dst + base + i) = pack4(a);
    *(uint64_t*)(dst + base + i + 4) = pack4(b2);
}

// cvt_w4 (small ws): weights only.  grid (512, 4).
__global__ __launch_bounds__(256) void cvt_w4(const float* __restrict__ w0,
                                              const float* __restrict__ w1,
                                              const float* __restrict__ w2,
                                              const float* __restrict__ w3,
                                              uint16_t* __restrict__ dst) {
    const float* srcs[4] = {w0, w1, w2, w3};
    const float* src = srcs[blockIdx.y];
    uint16_t* d = dst + (size_t)blockIdx.y * DM * DM;
    int i = (blockIdx.x * 256 + threadIdx.x) * 8;
    float4 a = *(const float4*)(src + i);
    float4 b2 = *(const float4*)(src + i + 4);
    *(uint64_t*)(d + i) = pack4(a);
    *(uint64_t*)(d + i + 4) = pack4(b2);
}

// ---------------------------------------------------------------------------
// QKV projection GEMM (unchanged from round 4): BK=64, gload_lds staging.
// AF32=1: A fp32 reg-convert staging.  AF32=0: A bf16 gload.
// z=0,1 -> (B,H,S,D); z=2 -> (B,H,D,S) via LDS-transpose epilogue.
// ---------------------------------------------------------------------------
template <int AF32>
__global__ __launch_bounds__(256) void gemm_qkv(const float* __restrict__ qa,
                                                const float* __restrict__ ka,
                                                const float* __restrict__ va,
                                                const uint16_t* __restrict__ xb,
                                                const uint16_t* __restrict__ Wb,
                                                uint16_t* __restrict__ Qb,
                                                uint16_t* __restrict__ Kb,
                                                uint16_t* __restrict__ Vt) {
    constexpr int BK = 64, ALD = AF32 ? 72 : 64;
    __shared__ __align__(16) uint16_t smem[17408];
    uint16_t* Ah = smem;
    uint16_t* Bh = smem + (AF32 ? 9216 : 8192);
    const int tid = threadIdx.x, lane = tid & 63, wid = tid >> 6;
    const int lr = lane & 15, lg = lane >> 4;
    const int m0 = blockIdx.x * 128, n0 = blockIdx.y * 128, z = blockIdx.z;
    const int wr = (wid >> 1) * 64, wc = (wid & 1) * 64;

    const float* Af = z == 0 ? qa : (z == 1 ? ka : va);
    const uint16_t* Ab = xb + (size_t)z * NQ;
    const uint16_t* W = Wb + (size_t)z * (DM * DM);

    f32x4 acc[4][4] = {};

    for (int kb = 0; kb < DM / BK; ++kb) {
        if constexpr (AF32) {
#pragma unroll
            for (int i = 0; i < 8; ++i) {
                int f = tid + i * 256;
                int row = f >> 4, c4 = (f & 15) * 4;
                float4 vv = *(const float4*)(Af + (size_t)(m0 + row) * DM + kb * BK + c4);
                *(uint64_t*)&Ah[row * ALD + c4] = pack4(vv);
            }
        } else {
#pragma unroll
            for (int p = 0; p < 4; ++p) {
                int row = p * 32 + (tid >> 3), ce = (tid & 7) * 8;
                GLOAD16(Ab + (size_t)(m0 + row) * DM + kb * BK + ce, Ah + row * 64 + ce);
            }
        }
#pragma unroll
        for (int p = 0; p < 4; ++p) {
            int row = p * 32 + (tid >> 3), ce = (tid & 7) * 8;
            GLOAD16(W + (size_t)(n0 + row) * DM + kb * BK + ce, Bh + row * 64 + ce);
        }
        __syncthreads();

        bf16x8 af[4][2], bw[4][2];
#pragma unroll
        for (int i = 0; i < 4; ++i)
#pragma unroll
            for (int ks = 0; ks < 2; ++ks) {
                af[i][ks] = ldfrag(&Ah[(wr + i * 16 + lr) * ALD + ks * 32 + lg * 8]);
                bw[i][ks] = ldfrag(&Bh[(wc + i * 16 + lr) * 64 + ks * 32 + lg * 8]);
            }
#pragma unroll
        for (int ks = 0; ks < 2; ++ks)
#pragma unroll
            for (int mi = 0; mi < 4; ++mi)
#pragma unroll
                for (int ni = 0; ni < 4; ++ni)
                    acc[mi][ni] = MFMA16(af[mi][ks], bw[ni][ks], acc[mi][ni]);
        __syncthreads();
    }

    if (z != 2) {
        uint16_t* Cp = z == 0 ? Qb : Kb;
#pragma unroll
        for (int mi = 0; mi < 4; ++mi)
#pragma unroll
            for (int ni = 0; ni < 4; ++ni)
#pragma unroll
                for (int r = 0; r < 4; ++r) {
                    int gm = m0 + wr + mi * 16 + lg * 4 + r;
                    int gn = n0 + wc + ni * 16 + lr;
                    int b = gm >> 10, s = gm & 1023, h = gn >> 6, d = gn & 63;
                    Cp[((size_t)(b * H + h) * S + s) * D + d] = f2bf_bits(acc[mi][ni][r]);
                }
    } else {
        // ---- LDS-transpose epilogue: coalesced (B,H,D,S) stores ----
        uint16_t* T = smem; // [128][136]
#pragma unroll
        for (int mi = 0; mi < 4; ++mi)
#pragma unroll
            for (int ni = 0; ni < 4; ++ni) {
                int row = wc + ni * 16 + lr;
                int colb = wr + mi * 16 + lg * 4;
                *(uint64_t*)&T[row * 136 + colb] = pack4f(acc[mi][ni]);
            }
        __syncthreads();
        const int b = m0 >> 10, s0b = m0 & 1023;
#pragma unroll
        for (int p = 0; p < 8; ++p) {
            int row = p * 16 + (tid >> 4), sl = tid & 15;
            int h = (n0 + row) >> 6, d = (n0 + row) & 63;
            u16x8 val = *(u16x8*)&T[row * 136 + sl * 8];
            *(u16x8*)&Vt[((size_t)(b * H + h) * D + d) * S + s0b + sl * 8] = val;
        }
    }
}

// ---------------------------------------------------------------------------
// O GEMM v2: out = ctx @ Wo^T, 128x64 tiles -> 512 blocks (2/CU).
// ---------------------------------------------------------------------------
__global__ __launch_bounds__(256) void gemm_o(const uint16_t* __restrict__ ctx,
                                              const uint16_t* __restrict__ Wo,
                                              float* __restrict__ out) {
    constexpr int BK = 64;
    __shared__ __align__(16) uint16_t smem[(128 + 64) * BK];
    uint16_t* Ah = smem;            // 128 x 64
    uint16_t* Bh = smem + 128 * 64; // 64 x 64
    const int tid = threadIdx.x, lane = tid & 63, wid = tid >> 6;
    const int lr = lane & 15, lg = lane >> 4;
    const int m0 = blockIdx.x * 128, n0 = blockIdx.y * 64;
    const int wr = (wid >> 1) * 64, wc = (wid & 1) * 32;

    f32x4 acc[4][2] = {};

    for (int kb = 0; kb < DM / BK; ++kb) {
#pragma unroll
        for (int p = 0; p < 4; ++p) {
            int row = p * 32 + (tid >> 3), ce = (tid & 7) * 8;
            GLOAD16(ctx + (size_t)(m0 + row) * DM + kb * BK + ce, Ah + row * 64 + ce);
        }
#pragma unroll
        for (int p = 0; p < 2; ++p) {
            int row = p * 32 + (tid >> 3), ce = (tid & 7) * 8;
            GLOAD16(Wo + (size_t)(n0 + row) * DM + kb * BK + ce, Bh + row * 64 + ce);
        }
        __syncthreads();

        bf16x8 af[4][2], bw[2][2];
#pragma unroll
        for (int i = 0; i < 4; ++i)
#pragma unroll
            for (int ks = 0; ks < 2; ++ks)
                af[i][ks] = ldfrag(&Ah[(wr + i * 16 + lr) * 64 + ks * 32 + lg * 8]);
#pragma unroll
        for (int i = 0; i < 2; ++i)
#pragma unroll
            for (int ks = 0; ks < 2; ++ks)
                bw[i][ks] = ldfrag(&Bh[(wc + i * 16 + lr) * 64 + ks * 32 + lg * 8]);
#pragma unroll
        for (int ks = 0; ks < 2; ++ks)
#pragma unroll
            for (int mi = 0; mi < 4; ++mi)
#pragma unroll
                for (int ni = 0; ni < 2; ++ni)
                    acc[mi][ni] = MFMA16(af[mi][ks], bw[ni][ks], acc[mi][ni]);
        __syncthreads();
    }

#pragma unroll
    for (int mi = 0; mi < 4; ++mi)
#pragma unroll
        for (int ni = 0; ni < 2; ++ni)
#pragma unroll
            for (int r = 0; r < 4; ++r) {
                int gm = m0 + wr + mi * 16 + lg * 4 + r;
                int gn = n0 + wc + ni * 16 + lr;
                out[(size_t)gm * DM + gn] = acc[mi][ni][r];
            }
}

// ---------------------------------------------------------------------------
// Fused attention v5: key-split waves for 2x TLP.
// Grid 2048 (XCD-bijective swizzle), block = 4 waves: (qg in {0,1}) x (kh in {0,1}).
// Each wave: 16 q-rows, 512 keys.  Direct global K/V loads (L2-resident).
// Cross-wave lsum and ctx combines via LDS (2 barriers total).
// Attn stores: nontemporal float4.
// ---------------------------------------------------------------------------
__global__ __launch_bounds__(256, 8) void attn_fused(const uint16_t* __restrict__ Qb,
                                                     const uint16_t* __restrict__ Kb,
                                                     const uint16_t* __restrict__ Vt,
                                                     float* __restrict__ attn,
                                                     uint16_t* __restrict__ ctx) {
    __shared__ __align__(16) float pf[4][16 * 36];   // per-wave P tile fp32
    __shared__ __align__(16) float redc[2][16 * 68]; // per-qg ctx partial
    __shared__ float redl[2][2][16];                 // lsum partials
    const int tid = threadIdx.x, lane = tid & 63, wid = tid >> 6;
    const int lr = lane & 15, lg = lane >> 4;
    const int qg = wid >> 1, kh = wid & 1;
    const int wg = blockIdx.x;
    const int xcd = wg & 7, rr = wg >> 3;
    const int qt = rr & 31, bh = xcd + 8 * (rr >> 5);
    const int q0 = qt * 32 + qg * 16;
    const int kb0 = kh * 512;

    const uint16_t* Qp = Qb + ((size_t)bh * S + q0) * D;
    const bf16x8 aq0 = ldfrag(Qp + lr * D + lg * 8);
    const bf16x8 aq1 = ldfrag(Qp + lr * D + 32 + lg * 8);

    const uint16_t* Kbase = Kb + ((size_t)bh * S + kb0) * D;
    const uint16_t* Vbase = Vt + (size_t)bh * D * S + kb0;
    constexpr float CEXP = 0.125f * 1.44269504088896340736f; // (1/sqrt(D))*log2(e)

    // ---- pass 1: row sums of exp over this wave's 512 keys ----
    float lsum[4] = {0.f, 0.f, 0.f, 0.f};
    for (int kc = 0; kc < 16; ++kc) {
        const uint16_t* Kp = Kbase + (size_t)kc * 32 * D;
        bf16x8 k00 = ldfrag(Kp + lr * D + lg * 8);
        bf16x8 k01 = ldfrag(Kp + lr * D + 32 + lg * 8);
        bf16x8 k10 = ldfrag(Kp + (16 + lr) * D + lg * 8);
        bf16x8 k11 = ldfrag(Kp + (16 + lr) * D + 32 + lg * 8);
        f32x4 s0 = {}, s1 = {};
        s0 = MFMA16(aq0, k00, s0);
        s0 = MFMA16(aq1, k01, s0);
        s1 = MFMA16(aq0, k10, s1);
        s1 = MFMA16(aq1, k11, s1);
#pragma unroll
        for (int r = 0; r < 4; ++r)
            lsum[r] += exp2f(s0[r] * CEXP) + exp2f(s1[r] * CEXP);
    }
#pragma unroll
    for (int r = 0; r < 4; ++r) {
        float v = lsum[r];
        v += __shfl_xor(v, 1);
        v += __shfl_xor(v, 2);
        v += __shfl_xor(v, 4);
        v += __shfl_xor(v, 8);
        lsum[r] = v;
    }
    if (lr == 0) {
#pragma unroll
        for (int r = 0; r < 4; ++r) redl[qg][kh][lg * 4 + r] = lsum[r];
    }
    __syncthreads();
    float linv[4];
#pragma unroll
    for (int r = 0; r < 4; ++r) linv[r] = 1.0f / (lsum[r] + redl[qg][kh ^ 1][lg * 4 + r]);

    // ---- pass 2: attn write + partial PV over this wave's 512 keys ----
    f32x4 cacc[4] = {};
    float* attn_base = attn + (size_t)bh * S * S + (size_t)q0 * S + kb0;
    float* pfw = pf[wid];

    for (int kc = 0; kc < 16; ++kc) {
        const uint16_t* Kp = Kbase + (size_t)kc * 32 * D;
        bf16x8 k00 = ldfrag(Kp + lr * D + lg * 8);
        bf16x8 k01 = ldfrag(Kp + lr * D + 32 + lg * 8);
        bf16x8 k10 = ldfrag(Kp + (16 + lr) * D + lg * 8);
        bf16x8 k11 = ldfrag(Kp + (16 + lr) * D + 32 + lg * 8);
        bf16x8 bv[4];
#pragma unroll
        for (int dt = 0; dt < 4; ++dt)
            bv[dt] = ldfrag(Vbase + (size_t)(dt * 16 + lr) * S + kc * 32 + lg * 8);
        f32x4 s0 = {}, s1 = {};
        s0 = MFMA16(aq0, k00, s0);
        s0 = MFMA16(aq1, k01, s0);
        s1 = MFMA16(aq0, k10, s1);
        s1 = MFMA16(aq1, k11, s1);
#pragma unroll
        for (int r = 0; r < 4; ++r) {
            pfw[(lg * 4 + r) * 36 + lr] = exp2f(s0[r] * CEXP) * linv[r];
            pfw[(lg * 4 + r) * 36 + 16 + lr] = exp2f(s1[r] * CEXP) * linv[r];
        }
        asm volatile("s_waitcnt lgkmcnt(0)" ::: "memory"); // wave-private pf ready
        // nontemporal coalesced attn stores (write-once data, keep L2 for K/V)
        {
            const float* rp = &pfw[(lane >> 2) * 36 + (lane & 3) * 4];
            f32x4 a0 = *(const f32x4*)rp;
            f32x4 a1 = *(const f32x4*)(rp + 16);
            float* gp = attn_base + (size_t)(lane >> 2) * S + kc * 32 + (lane & 3) * 4;
            __builtin_nontemporal_store(a0, (f32x4*)gp);
            __builtin_nontemporal_store(a1, (f32x4*)(gp + 16));
        }
        // PV A-fragment from pf (row=lr q-row, keys lg*8..lg*8+7)
        bf16x8 pa;
        {
            const f32x4 p0 = *(const f32x4*)&pfw[lr * 36 + lg * 8];
            const f32x4 p1 = *(const f32x4*)&pfw[lr * 36 + lg * 8 + 4];
            u16x8 pu;
#pragma unroll
            for (int j = 0; j < 4; ++j) {
                pu[j] = f2bf_bits(p0[j]);
                pu[4 + j] = f2bf_bits(p1[j]);
            }
            pa = __builtin_bit_cast(bf16x8, pu);
        }
#pragma unroll
        for (int dt = 0; dt < 4; ++dt)
            cacc[dt] = MFMA16(pa, bv[dt], cacc[dt]);
    }

    // ---- cross-kh PV combine + ctx store ----
    if (kh == 1) {
#pragma unroll
        for (int dt = 0; dt < 4; ++dt)
#pragma unroll
            for (int r = 0; r < 4; ++r)
                redc[qg][(lg * 4 + r) * 68 + dt * 16 + lr] = cacc[dt][r];
    }
    __syncthreads();
    if (kh == 0) {
        const int b = bh >> 4, h = bh & 15;
#pragma unroll
        for (int dt = 0; dt < 4; ++dt)
#pragma unroll
            for (int r = 0; r < 4; ++r) {
                float v = cacc[dt][r] + redc[qg][(lg * 4 + r) * 68 + dt * 16 + lr];
                int q = q0 + lg * 4 + r;
                int d = dt * 16 + lr;
                ctx[((size_t)b * S + q) * DM + h * D + d] = f2bf_bits(v);
            }
    }
}

// ---------------------------------------------------------------------------
extern "C" void kernel_launch(void* const* d_in, const int* in_sizes, int n_in,
                              void* d_out, int out_size, void* d_ws, size_t ws_size,
                              hipStream_t stream) {
    const float* q = (const float*)d_in[0];
    const float* k = (const float*)d_in[1];
    const float* v = (const float*)d_in[2];
    const float* Wq = (const float*)d_in[3];
    const float* Wk = (const float*)d_in[4];
    const float* Wv = (const float*)d_in[5];
    const float* Wo = (const float*)d_in[6];

    float* out = (float*)d_out;
    float* attn = out + (size_t)B * S * DM;

    const bool big = ws_size >= (size_t)7 * NQ * 2 + 256;
    dim3 gg(M / 128, DM / 128, 3);

    if (big) {
        uint16_t* xb = (uint16_t*)d_ws;      // 3*NQ (xq,xk,xv)
        uint16_t* Wb = xb + 3 * NQ;          // NQ   (Wq,Wk,Wv,Wo)
        uint16_t* Qb = Wb + NQ;
        uint16_t* Kb = Qb + NQ;
        uint16_t* Vt = Kb + NQ;
        uint16_t* ctx = xb; // xq dead after gemm_qkv
        cvt_all<<<dim3(2048, 7), 256, 0, stream>>>(q, k, v, Wq, Wk, Wv, Wo, xb);
        gemm_qkv<0><<<gg, 256, 0, stream>>>(q, k, v, xb, Wb, Qb, Kb, Vt);
        attn_fused<<<dim3(2048), 256, 0, stream>>>(Qb, Kb, Vt, attn, ctx);
        gemm_o<<<dim3(M / 128, DM / 64), 256, 0, stream>>>(ctx, Wb + (size_t)3 * DM * DM, out);
    } else {
        uint16_t* Qb = (uint16_t*)d_ws;
        uint16_t* Kb = Qb + NQ;
        uint16_t* Vt = Kb + NQ;
        uint16_t* ctx = Vt + NQ;
        uint16_t* Wb = ctx + NQ;
        cvt_w4<<<dim3(512, 4), 256, 0, stream>>>(Wq, Wk, Wv, Wo, Wb);
        gemm_qkv<1><<<gg, 256, 0, stream>>>(q, k, v, nullptr, Wb, Qb, Kb, Vt);
        attn_fused<<<dim3(2048), 256, 0, stream>>>(Qb, Kb, Vt, attn, ctx);
        gemm_o<<<dim3(M / 128, DM / 64), 256, 0, stream>>>(ctx, Wb + (size_t)3 * DM * DM, out);
    }
}